// Round 1
// baseline (316.910 us; speedup 1.0000x reference)
//
#include <hip/hip_runtime.h>
#include <stdint.h>

#define D_DIM 512

typedef __attribute__((ext_vector_type(8))) short bf16x8;
typedef __attribute__((ext_vector_type(4))) float f32x4;
typedef __attribute__((ext_vector_type(4))) short short4_t;
typedef __attribute__((ext_vector_type(4))) float float4_t;

__device__ __forceinline__ unsigned short f2bf(float f) {
  unsigned u = __float_as_uint(f);
  u += 0x7FFFu + ((u >> 16) & 1u);
  return (unsigned short)(u >> 16);
}

__device__ __forceinline__ float tanh_fast(float x) {
  float e = __expf(2.0f * x);
  return 1.0f - 2.0f / (e + 1.0f);
}

// ---------------- small utility kernels ----------------

__global__ void cvt_f32_bf16_k(const float* __restrict__ in, unsigned short* __restrict__ out, int n4) {
  int i = blockIdx.x * blockDim.x + threadIdx.x;
  if (i < n4) {
    float4_t v = ((const float4_t*)in)[i];
    short4_t s;
    s.x = (short)f2bf(v.x); s.y = (short)f2bf(v.y);
    s.z = (short)f2bf(v.z); s.w = (short)f2bf(v.w);
    ((short4_t*)out)[i] = s;
  }
}

__global__ void prep_cluster_k(const int* __restrict__ vn, const int* __restrict__ nid,
                               int* __restrict__ cl, int* __restrict__ counts, int B) {
  int i = blockIdx.x * blockDim.x + threadIdx.x;
  if (i < B) {
    int c = vn[2 * nid[i] + 1];
    cl[i] = c;
    atomicAdd(&counts[c], 1);
  }
}

__global__ void prefix_k(const int* __restrict__ counts, int* __restrict__ starts,
                         int* __restrict__ cursor, int C) {
  __shared__ int sh[1024];
  int t = threadIdx.x;
  int v = (t < C) ? counts[t] : 0;
  sh[t] = v;
  __syncthreads();
  for (int off = 1; off < 1024; off <<= 1) {
    int x = (t >= off) ? sh[t - off] : 0;
    __syncthreads();
    sh[t] += x;
    __syncthreads();
  }
  if (t < C) { int st = sh[t] - v; starts[t] = st; cursor[t] = st; }
  if (t == 1023) starts[C] = sh[1023];
}

__global__ void scatter_k(const int* __restrict__ cl, int* __restrict__ cursor,
                          int* __restrict__ order, int B) {
  int i = blockIdx.x * blockDim.x + threadIdx.x;
  if (i < B) {
    int pos = atomicAdd(&cursor[cl[i]], 1);
    order[pos] = i;
  }
}

__device__ __forceinline__ unsigned enc_f(float f) {
  unsigned u = __float_as_uint(f);
  return (u & 0x80000000u) ? ~u : (u | 0x80000000u);
}
__device__ __forceinline__ float dec_f(unsigned u) {
  return __uint_as_float((u & 0x80000000u) ? (u & 0x7FFFFFFFu) : ~u);
}

__global__ void seg_max_k(const float* __restrict__ score, const int* __restrict__ cl,
                          unsigned* __restrict__ smax, int B) {
  int i = blockIdx.x * blockDim.x + threadIdx.x;
  if (i < B) atomicMax(&smax[cl[i]], enc_f(score[i]));
}

__global__ void seg_expsum_k(const float* __restrict__ score, const int* __restrict__ cl,
                             const unsigned* __restrict__ smax, float* __restrict__ ev,
                             float* __restrict__ denom, int B) {
  int i = blockIdx.x * blockDim.x + threadIdx.x;
  if (i < B) {
    int c = cl[i];
    float x = __expf(score[i] - dec_f(smax[c]));
    ev[i] = x;
    atomicAdd(&denom[c], x);
  }
}

__global__ __launch_bounds__(512)
void ctx_k(const float* __restrict__ h, const float* __restrict__ ev,
           const int* __restrict__ order, const int* __restrict__ starts,
           const float* __restrict__ denom, float* __restrict__ ctx) {
  int c = blockIdx.x;
  int d = threadIdx.x;
  int s0 = starts[c], s1 = starts[c + 1];
  float acc = 0.f;
  for (int j = s0; j < s1; ++j) {
    int i = order[j];
    acc += ev[i] * h[(size_t)i * D_DIM + d];
  }
  ctx[(size_t)c * D_DIM + d] = acc / denom[c];
}

// ---------------- fused bf16 MFMA GEMM (C = A @ Bw^T), BN = 512 ----------------
// EPI 0: out[m][n] = acc + bias[n]                  (qb = g@Wq^T + attn_bias)
// EPI 1: score[m]  = sum_n tanh(acc + qb[cl[m]][n]) * Ws[n] + bs
// EPI 2: out[m][n] = tanh(acc + bias[n])            (final output)
template<int BM, int EPI>
__global__ __launch_bounds__(512)
void gemm_bt_k(const float* __restrict__ A, const unsigned short* __restrict__ Bw, int M,
               const float* __restrict__ qb, const int* __restrict__ cl,
               const float* __restrict__ Ws, const float* __restrict__ bsp,
               const float* __restrict__ bias, float* __restrict__ out)
{
  constexpr int BK = 32;
  constexpr int MFR = BM / 16;
  __shared__ unsigned short As[BM][BK];
  __shared__ unsigned short Bs[512][BK];
  __shared__ float red[BM][8];
  __shared__ int clds[BM];

  const int t = threadIdx.x;
  const int lane = t & 63;
  const int w = t >> 6;          // wave 0..7, owns cols [w*64, w*64+64)
  const int m0 = blockIdx.x * BM;
  const int l15 = lane & 15;
  const int l4 = lane >> 4;

  if (EPI == 1) {
    if (t < BM) {
      int gm = m0 + t;
      clds[t] = (gm < M) ? cl[gm] : 0;
    }
  }

  f32x4 acc[MFR][4];
  #pragma unroll
  for (int mi = 0; mi < MFR; ++mi)
    #pragma unroll
    for (int ni = 0; ni < 4; ++ni)
      acc[mi][ni] = (f32x4){0.f, 0.f, 0.f, 0.f};

  for (int k0 = 0; k0 < 512; k0 += BK) {
    // stage A tile (f32 -> bf16), BM*8 threads x float4
    if (t < BM * 8) {
      int r = t >> 3, kq = (t & 7) * 4;
      int gm = m0 + r;
      float4_t v = (float4_t){0.f, 0.f, 0.f, 0.f};
      if (gm < M) v = *(const float4_t*)(&A[(size_t)gm * 512 + k0 + kq]);
      short4_t s;
      s.x = (short)f2bf(v.x); s.y = (short)f2bf(v.y);
      s.z = (short)f2bf(v.z); s.w = (short)f2bf(v.w);
      *(short4_t*)(&As[r][kq]) = s;
    }
    // stage B tile (bf16, 512 rows x 32): 512 threads x 4 x 16B
    #pragma unroll
    for (int cc = 0; cc < 4; ++cc) {
      int tt = cc * 512 + t;
      int n = tt >> 2, kp = (tt & 3) * 8;
      *(bf16x8*)(&Bs[n][kp]) = *(const bf16x8*)(&Bw[n * 512 + k0 + kp]);
    }
    __syncthreads();

    bf16x8 af[MFR], bfv[4];
    #pragma unroll
    for (int mi = 0; mi < MFR; ++mi)
      af[mi] = *(const bf16x8*)(&As[mi * 16 + l15][l4 * 8]);
    #pragma unroll
    for (int ni = 0; ni < 4; ++ni)
      bfv[ni] = *(const bf16x8*)(&Bs[w * 64 + ni * 16 + l15][l4 * 8]);
    #pragma unroll
    for (int mi = 0; mi < MFR; ++mi)
      #pragma unroll
      for (int ni = 0; ni < 4; ++ni)
        acc[mi][ni] = __builtin_amdgcn_mfma_f32_16x16x32_bf16(af[mi], bfv[ni], acc[mi][ni], 0, 0, 0);
    __syncthreads();
  }

  if (EPI == 0 || EPI == 2) {
    #pragma unroll
    for (int mi = 0; mi < MFR; ++mi) {
      #pragma unroll
      for (int r = 0; r < 4; ++r) {
        int row = mi * 16 + l4 * 4 + r;
        int gm = m0 + row;
        if (gm < M) {
          #pragma unroll
          for (int ni = 0; ni < 4; ++ni) {
            int col = w * 64 + ni * 16 + l15;
            float v = acc[mi][ni][r] + bias[col];
            if (EPI == 2) v = tanh_fast(v);
            out[(size_t)gm * 512 + col] = v;
          }
        }
      }
    }
  } else {
    // EPI == 1: fused additive-attention score
    float rs[MFR][4];
    #pragma unroll
    for (int mi = 0; mi < MFR; ++mi)
      #pragma unroll
      for (int r = 0; r < 4; ++r) rs[mi][r] = 0.f;

    #pragma unroll
    for (int mi = 0; mi < MFR; ++mi) {
      #pragma unroll
      for (int r = 0; r < 4; ++r) {
        int row = mi * 16 + l4 * 4 + r;
        int c = clds[row];
        const float* qrow = &qb[(size_t)c * 512];
        #pragma unroll
        for (int ni = 0; ni < 4; ++ni) {
          int col = w * 64 + ni * 16 + l15;
          float x = acc[mi][ni][r] + qrow[col];
          rs[mi][r] += tanh_fast(x) * Ws[col];
        }
      }
    }
    // reduce across the 16 lanes holding the same row (different cols)
    #pragma unroll
    for (int mi = 0; mi < MFR; ++mi) {
      #pragma unroll
      for (int r = 0; r < 4; ++r) {
        float s = rs[mi][r];
        s += __shfl_xor(s, 1);
        s += __shfl_xor(s, 2);
        s += __shfl_xor(s, 4);
        s += __shfl_xor(s, 8);
        if (l15 == 0) red[mi * 16 + l4 * 4 + r][w] = s;
      }
    }
    __syncthreads();
    if (t < BM) {
      float s = red[t][0] + red[t][1] + red[t][2] + red[t][3] +
                red[t][4] + red[t][5] + red[t][6] + red[t][7] + bsp[0];
      int gm = m0 + t;
      if (gm < M) out[gm] = s;
    }
  }
}

// ---------------- host side ----------------

extern "C" void kernel_launch(void* const* d_in, const int* in_sizes, int n_in,
                              void* d_out, int out_size, void* d_ws, size_t ws_size,
                              hipStream_t stream) {
  const float* h  = (const float*)d_in[0];
  const float* g  = (const float*)d_in[1];
  const int*   vn = (const int*)d_in[2];
  const int*   nid= (const int*)d_in[3];
  const float* Wq = (const float*)d_in[4];
  const float* Wk = (const float*)d_in[5];
  const float* ab = (const float*)d_in[6];
  const float* Ws = (const float*)d_in[7];
  const float* bs = (const float*)d_in[8];
  const float* W  = (const float*)d_in[9];
  const float* b  = (const float*)d_in[10];

  const int B = in_sizes[3];          // 100000
  const int C = in_sizes[1] / D_DIM;  // 1000

  char* wsb = (char*)d_ws;
  size_t off = 0;
  auto alloc = [&](size_t bytes) -> void* {
    void* p = wsb + off;
    off += (bytes + 255) & ~(size_t)255;
    return p;
  };

  unsigned short* Wk_bf = (unsigned short*)alloc((size_t)512 * 512 * 2);
  unsigned short* Wq_bf = (unsigned short*)alloc((size_t)512 * 512 * 2);
  unsigned short* W_bf  = (unsigned short*)alloc((size_t)512 * 512 * 2);
  float* qb    = (float*)alloc((size_t)C * 512 * 4);
  float* score = (float*)alloc((size_t)B * 4);
  float* ev    = (float*)alloc((size_t)B * 4);
  int*   cl    = (int*)alloc((size_t)B * 4);
  int*   order = (int*)alloc((size_t)B * 4);
  float* ctx   = (float*)alloc((size_t)C * 512 * 4);
  int*      counts = (int*)alloc((size_t)C * 4);
  unsigned* smax   = (unsigned*)alloc((size_t)C * 4);
  float*    denom  = (float*)alloc((size_t)C * 4);
  int* starts = (int*)alloc((size_t)(C + 1) * 4);
  int* cursor = (int*)alloc((size_t)C * 4);
  (void)ws_size; (void)n_in; (void)out_size;

  // zero counts..denom (contiguous region)
  size_t zlen = (size_t)((char*)denom - (char*)counts) + (size_t)C * 4;
  hipMemsetAsync(counts, 0, zlen, stream);

  const int n4w = 512 * 512 / 4;
  cvt_f32_bf16_k<<<(n4w + 255) / 256, 256, 0, stream>>>(Wk, Wk_bf, n4w);
  cvt_f32_bf16_k<<<(n4w + 255) / 256, 256, 0, stream>>>(Wq, Wq_bf, n4w);
  cvt_f32_bf16_k<<<(n4w + 255) / 256, 256, 0, stream>>>(W, W_bf, n4w);

  prep_cluster_k<<<(B + 255) / 256, 256, 0, stream>>>(vn, nid, cl, counts, B);
  prefix_k<<<1, 1024, 0, stream>>>(counts, starts, cursor, C);
  scatter_k<<<(B + 255) / 256, 256, 0, stream>>>(cl, cursor, order, B);

  // qb = g @ Wq^T + attn_bias
  gemm_bt_k<64, 0><<<(C + 63) / 64, 512, 0, stream>>>(g, Wq_bf, C, nullptr, nullptr,
                                                      nullptr, nullptr, ab, qb);
  // score = tanh(h@Wk^T + qb[cl]) . Ws + bs   (the big GEMM)
  gemm_bt_k<64, 1><<<(B + 63) / 64, 512, 0, stream>>>(h, Wk_bf, B, qb, cl,
                                                      Ws, bs, nullptr, score);
  seg_max_k<<<(B + 255) / 256, 256, 0, stream>>>(score, cl, smax, B);
  seg_expsum_k<<<(B + 255) / 256, 256, 0, stream>>>(score, cl, smax, ev, denom, B);
  ctx_k<<<C, 512, 0, stream>>>(h, ev, order, starts, denom, ctx);

  // out = tanh(ctx @ W^T + b)
  gemm_bt_k<64, 2><<<(C + 63) / 64, 512, 0, stream>>>(ctx, W_bf, C, nullptr, nullptr,
                                                      nullptr, nullptr, b, (float*)d_out);
}

// Round 2
// 265.604 us; speedup vs baseline: 1.1932x; 1.1932x over previous
//
#include <hip/hip_runtime.h>
#include <stdint.h>

#define D_DIM 512

typedef __attribute__((ext_vector_type(8))) short bf16x8;
typedef __attribute__((ext_vector_type(4))) float f32x4;
typedef __attribute__((ext_vector_type(4))) short short4_t;
typedef __attribute__((ext_vector_type(4))) float float4_t;

__device__ __forceinline__ unsigned short f2bf(float f) {
  unsigned u = __float_as_uint(f);
  u += 0x7FFFu + ((u >> 16) & 1u);
  return (unsigned short)(u >> 16);
}

__device__ __forceinline__ float bf2f(unsigned short s) {
  return __uint_as_float(((unsigned)s) << 16);
}

__device__ __forceinline__ float tanh_fast(float x) {
  float e = __expf(2.0f * x);
  return 1.0f - 2.0f / (e + 1.0f);
}

#define GLOAD_LDS16(gsrc, ldst) \
  __builtin_amdgcn_global_load_lds((const __attribute__((address_space(1))) void*)(gsrc), \
                                   (__attribute__((address_space(3))) void*)(ldst), 16, 0, 0)

// ---------------- small utility kernels ----------------

__global__ void cvt_f32_bf16_k(const float* __restrict__ in, unsigned short* __restrict__ out, int n4) {
  int i = blockIdx.x * blockDim.x + threadIdx.x;
  if (i < n4) {
    float4_t v = ((const float4_t*)in)[i];
    short4_t s;
    s.x = (short)f2bf(v.x); s.y = (short)f2bf(v.y);
    s.z = (short)f2bf(v.z); s.w = (short)f2bf(v.w);
    ((short4_t*)out)[i] = s;
  }
}

__global__ void prep_cluster_k(const int* __restrict__ vn, const int* __restrict__ nid,
                               int* __restrict__ cl, int* __restrict__ counts, int B) {
  int i = blockIdx.x * blockDim.x + threadIdx.x;
  if (i < B) {
    int c = vn[2 * nid[i] + 1];
    cl[i] = c;
    atomicAdd(&counts[c], 1);
  }
}

__global__ void prefix_k(const int* __restrict__ counts, int* __restrict__ starts,
                         int* __restrict__ cursor, int C) {
  __shared__ int sh[1024];
  int t = threadIdx.x;
  int v = (t < C) ? counts[t] : 0;
  sh[t] = v;
  __syncthreads();
  for (int off = 1; off < 1024; off <<= 1) {
    int x = (t >= off) ? sh[t - off] : 0;
    __syncthreads();
    sh[t] += x;
    __syncthreads();
  }
  if (t < C) { int st = sh[t] - v; starts[t] = st; cursor[t] = st; }
  if (t == 1023) starts[C] = sh[1023];
}

__global__ void scatter_k(const int* __restrict__ cl, int* __restrict__ cursor,
                          int* __restrict__ order, int B) {
  int i = blockIdx.x * blockDim.x + threadIdx.x;
  if (i < B) {
    int pos = atomicAdd(&cursor[cl[i]], 1);
    order[pos] = i;
  }
}

__device__ __forceinline__ unsigned enc_f(float f) {
  unsigned u = __float_as_uint(f);
  return (u & 0x80000000u) ? ~u : (u | 0x80000000u);
}
__device__ __forceinline__ float dec_f(unsigned u) {
  return __uint_as_float((u & 0x80000000u) ? (u & 0x7FFFFFFFu) : ~u);
}

__global__ void seg_max_k(const float* __restrict__ score, const int* __restrict__ cl,
                          unsigned* __restrict__ smax, int B) {
  int i = blockIdx.x * blockDim.x + threadIdx.x;
  if (i < B) atomicMax(&smax[cl[i]], enc_f(score[i]));
}

__global__ void seg_expsum_k(const float* __restrict__ score, const int* __restrict__ cl,
                             const unsigned* __restrict__ smax, float* __restrict__ ev,
                             float* __restrict__ denom, int B) {
  int i = blockIdx.x * blockDim.x + threadIdx.x;
  if (i < B) {
    int c = cl[i];
    float x = __expf(score[i] - dec_f(smax[c]));
    ev[i] = x;
    atomicAdd(&denom[c], x);
  }
}

__global__ __launch_bounds__(512)
void ctx_k(const unsigned short* __restrict__ hbf, const float* __restrict__ ev,
           const int* __restrict__ order, const int* __restrict__ starts,
           const float* __restrict__ denom, float* __restrict__ ctx) {
  int c = blockIdx.x;
  int d = threadIdx.x;
  int s0 = starts[c], s1 = starts[c + 1];
  float acc = 0.f;
  int j = s0;
  for (; j + 1 < s1; j += 2) {
    int i0 = order[j], i1 = order[j + 1];
    float e0 = ev[i0], e1 = ev[i1];
    float h0 = bf2f(hbf[(size_t)i0 * D_DIM + d]);
    float h1 = bf2f(hbf[(size_t)i1 * D_DIM + d]);
    acc += e0 * h0 + e1 * h1;
  }
  if (j < s1) {
    int i0 = order[j];
    acc += ev[i0] * bf2f(hbf[(size_t)i0 * D_DIM + d]);
  }
  ctx[(size_t)c * D_DIM + d] = acc / denom[c];
}

// ------------- m97-style bf16 MFMA GEMM: C128x128 tile, BK=64 -------------
// A: [M][512] bf16 (row-major), Bw: [512][512] bf16 (row n = output col n)
// grid = (4 N-blocks, ceil(M/128)); 256 threads (4 waves, 2x2 of 64x64)
// EPI 0: out[m][n] = acc + bias[n]
// EPI 1: atomicAdd(out[m], sum_n tanh(acc + qb[cl[m]][n]) * Ws[n])
// EPI 2: out[m][n] = tanh(acc + bias[n])
// LDS tiles hold 128 rows x 128 bytes, 16B-slot-swizzled: slot' = slot ^ (row&7).
// global_load_lds writes linearly; source address is pre-swizzled to match.
template<int EPI>
__global__ __launch_bounds__(256)
void gemm128_k(const unsigned short* __restrict__ Abf,
               const unsigned short* __restrict__ Bw, int M,
               const float* __restrict__ qb, const int* __restrict__ cl,
               const float* __restrict__ Ws, const float* __restrict__ bias,
               float* __restrict__ out)
{
  __shared__ unsigned short As[128 * 64];
  __shared__ unsigned short Bs[128 * 64];
  __shared__ float red[128][2];
  __shared__ int clds[128];

  const int t = threadIdx.x;
  const int lane = t & 63;
  const int w = t >> 6;             // wave 0..3
  const int wr = w >> 1, wc = w & 1;
  const int l15 = lane & 15, l4 = lane >> 4;
  const int n0 = blockIdx.x * 128;
  const int m0 = blockIdx.y * 128;

  if (EPI == 1 && t < 128) {
    int gm = m0 + t;
    clds[t] = (gm < M) ? cl[gm] : 0;
  }

  // staging geometry: 16 chunks of 1KB per tile; wave w stages chunks w*4..w*4+3
  // within a chunk: lane covers row = chunk*8 + (lane>>3), lds slot = lane&7;
  // source slot = (lane&7) ^ (row&7)   (inverse of the read-side swizzle)
  const int rin = lane >> 3;
  const int sl = lane & 7;

  // precompute per-lane source pointers (k0 advances by 128B per step)
  const unsigned short* srcA[4];
  const unsigned short* srcB[4];
  char* dstA[4];
  char* dstB[4];
  #pragma unroll
  for (int c = 0; c < 4; ++c) {
    int chunk = w * 4 + c;
    int row = chunk * 8 + rin;
    int slot = sl ^ (row & 7);
    int ga = m0 + row; if (ga > M - 1) ga = M - 1;
    srcA[c] = Abf + (size_t)ga * 512 + slot * 8;
    srcB[c] = Bw + (size_t)(n0 + row) * 512 + slot * 8;
    dstA[c] = ((char*)As) + chunk * 1024;
    dstB[c] = ((char*)Bs) + chunk * 1024;
  }

  // precompute fragment LDS byte offsets (loop-invariant over k0)
  int offA[4][2], offB[4][2];
  #pragma unroll
  for (int mi = 0; mi < 4; ++mi) {
    int row = wr * 64 + mi * 16 + l15;
    #pragma unroll
    for (int ks = 0; ks < 2; ++ks)
      offA[mi][ks] = row * 128 + (((ks * 4 + l4) ^ (row & 7)) * 16);
  }
  #pragma unroll
  for (int ni = 0; ni < 4; ++ni) {
    int row = wc * 64 + ni * 16 + l15;
    #pragma unroll
    for (int ks = 0; ks < 2; ++ks)
      offB[ni][ks] = row * 128 + (((ks * 4 + l4) ^ (row & 7)) * 16);
  }

  f32x4 acc[4][4];
  #pragma unroll
  for (int mi = 0; mi < 4; ++mi)
    #pragma unroll
    for (int ni = 0; ni < 4; ++ni)
      acc[mi][ni] = (f32x4){0.f, 0.f, 0.f, 0.f};

  for (int k0 = 0; k0 < 512; k0 += 64) {
    #pragma unroll
    for (int c = 0; c < 4; ++c) {
      GLOAD_LDS16(srcA[c] + k0, dstA[c]);
      GLOAD_LDS16(srcB[c] + k0, dstB[c]);
    }
    __syncthreads();

    #pragma unroll
    for (int ks = 0; ks < 2; ++ks) {
      bf16x8 af[4], bfv[4];
      #pragma unroll
      for (int mi = 0; mi < 4; ++mi)
        af[mi] = *(const bf16x8*)(((const char*)As) + offA[mi][ks]);
      #pragma unroll
      for (int ni = 0; ni < 4; ++ni)
        bfv[ni] = *(const bf16x8*)(((const char*)Bs) + offB[ni][ks]);
      #pragma unroll
      for (int mi = 0; mi < 4; ++mi)
        #pragma unroll
        for (int ni = 0; ni < 4; ++ni)
          acc[mi][ni] = __builtin_amdgcn_mfma_f32_16x16x32_bf16(af[mi], bfv[ni], acc[mi][ni], 0, 0, 0);
    }
    __syncthreads();
  }

  if (EPI == 0 || EPI == 2) {
    #pragma unroll
    for (int mi = 0; mi < 4; ++mi) {
      #pragma unroll
      for (int r = 0; r < 4; ++r) {
        int gm = m0 + wr * 64 + mi * 16 + l4 * 4 + r;
        if (gm < M) {
          #pragma unroll
          for (int ni = 0; ni < 4; ++ni) {
            int gcol = n0 + wc * 64 + ni * 16 + l15;
            float v = acc[mi][ni][r] + bias[gcol];
            if (EPI == 2) v = tanh_fast(v);
            out[(size_t)gm * 512 + gcol] = v;
          }
        }
      }
    }
  } else {
    // fused additive-attention partial score over this block's 128 cols
    #pragma unroll
    for (int mi = 0; mi < 4; ++mi) {
      #pragma unroll
      for (int r = 0; r < 4; ++r) {
        int rowt = wr * 64 + mi * 16 + l4 * 4 + r;
        int c = clds[rowt];
        const float* qrow = &qb[(size_t)c * 512 + n0 + wc * 64];
        float s = 0.f;
        #pragma unroll
        for (int ni = 0; ni < 4; ++ni) {
          int colw = ni * 16 + l15;
          float x = acc[mi][ni][r] + qrow[colw];
          s += tanh_fast(x) * Ws[n0 + wc * 64 + colw];
        }
        s += __shfl_xor(s, 1);
        s += __shfl_xor(s, 2);
        s += __shfl_xor(s, 4);
        s += __shfl_xor(s, 8);
        if (l15 == 0) red[rowt][wc] = s;
      }
    }
    __syncthreads();
    if (t < 128) {
      int gm = m0 + t;
      if (gm < M) atomicAdd(&out[gm], red[t][0] + red[t][1]);
    }
  }
}

// ---------------- host side ----------------

extern "C" void kernel_launch(void* const* d_in, const int* in_sizes, int n_in,
                              void* d_out, int out_size, void* d_ws, size_t ws_size,
                              hipStream_t stream) {
  const float* h  = (const float*)d_in[0];
  const float* g  = (const float*)d_in[1];
  const int*   vn = (const int*)d_in[2];
  const int*   nid= (const int*)d_in[3];
  const float* Wq = (const float*)d_in[4];
  const float* Wk = (const float*)d_in[5];
  const float* ab = (const float*)d_in[6];
  const float* Ws = (const float*)d_in[7];
  const float* W  = (const float*)d_in[9];
  const float* b  = (const float*)d_in[10];

  const int B = in_sizes[3];          // 100000
  const int C = in_sizes[1] / D_DIM;  // 1000

  char* wsb = (char*)d_ws;
  size_t off = 0;
  auto alloc = [&](size_t bytes) -> void* {
    void* p = wsb + off;
    off += (bytes + 255) & ~(size_t)255;
    return p;
  };

  unsigned short* hbf   = (unsigned short*)alloc((size_t)B * 512 * 2);
  unsigned short* gbf   = (unsigned short*)alloc((size_t)C * 512 * 2);
  unsigned short* ctxbf = (unsigned short*)alloc((size_t)C * 512 * 2);
  unsigned short* Wk_bf = (unsigned short*)alloc((size_t)512 * 512 * 2);
  unsigned short* Wq_bf = (unsigned short*)alloc((size_t)512 * 512 * 2);
  unsigned short* W_bf  = (unsigned short*)alloc((size_t)512 * 512 * 2);
  float* qb    = (float*)alloc((size_t)C * 512 * 4);
  float* ctx   = (float*)alloc((size_t)C * 512 * 4);
  float* score = (float*)alloc((size_t)B * 4);
  float* ev    = (float*)alloc((size_t)B * 4);
  int*   cl    = (int*)alloc((size_t)B * 4);
  int*   order = (int*)alloc((size_t)B * 4);
  int*      counts = (int*)alloc((size_t)C * 4);
  unsigned* smax   = (unsigned*)alloc((size_t)C * 4);
  float*    denom  = (float*)alloc((size_t)C * 4);
  int* starts = (int*)alloc((size_t)(C + 1) * 4);
  int* cursor = (int*)alloc((size_t)C * 4);
  (void)ws_size; (void)n_in; (void)out_size;

  // zero atomically-accumulated buffers each launch
  size_t zlen = (size_t)((char*)denom - (char*)counts) + (size_t)C * 4;
  hipMemsetAsync(counts, 0, zlen, stream);
  hipMemsetAsync(score, 0, (size_t)B * 4, stream);

  // conversions
  cvt_f32_bf16_k<<<(B * 512 / 4 + 255) / 256, 256, 0, stream>>>(h, hbf, B * 512 / 4);
  cvt_f32_bf16_k<<<(C * 512 / 4 + 255) / 256, 256, 0, stream>>>(g, gbf, C * 512 / 4);
  const int n4w = 512 * 512 / 4;
  cvt_f32_bf16_k<<<(n4w + 255) / 256, 256, 0, stream>>>(Wk, Wk_bf, n4w);
  cvt_f32_bf16_k<<<(n4w + 255) / 256, 256, 0, stream>>>(Wq, Wq_bf, n4w);
  cvt_f32_bf16_k<<<(n4w + 255) / 256, 256, 0, stream>>>(W, W_bf, n4w);

  prep_cluster_k<<<(B + 255) / 256, 256, 0, stream>>>(vn, nid, cl, counts, B);
  prefix_k<<<1, 1024, 0, stream>>>(counts, starts, cursor, C);
  scatter_k<<<(B + 255) / 256, 256, 0, stream>>>(cl, cursor, order, B);

  // qb = g @ Wq^T + attn_bias
  gemm128_k<0><<<dim3(4, (C + 127) / 128), 256, 0, stream>>>(
      gbf, Wq_bf, C, nullptr, nullptr, nullptr, ab, qb);

  // score[m] += sum over this N-block of tanh(h@Wk^T + qb[cl])·Ws  (bs dropped:
  // softmax is invariant to a constant shift)
  gemm128_k<1><<<dim3(4, (B + 127) / 128), 256, 0, stream>>>(
      hbf, Wk_bf, B, qb, cl, Ws, nullptr, score);

  seg_max_k<<<(B + 255) / 256, 256, 0, stream>>>(score, cl, smax, B);
  seg_expsum_k<<<(B + 255) / 256, 256, 0, stream>>>(score, cl, smax, ev, denom, B);
  ctx_k<<<C, 512, 0, stream>>>(hbf, ev, order, starts, denom, ctx);

  cvt_f32_bf16_k<<<(C * 512 / 4 + 255) / 256, 256, 0, stream>>>(ctx, ctxbf, C * 512 / 4);

  // out = tanh(ctx @ W^T + b)
  gemm128_k<2><<<dim3(4, (C + 127) / 128), 256, 0, stream>>>(
      ctxbf, W_bf, C, nullptr, nullptr, nullptr, b, (float*)d_out);
}

// Round 3
// 261.859 us; speedup vs baseline: 1.2102x; 1.0143x over previous
//
#include <hip/hip_runtime.h>
#include <stdint.h>

#define D_DIM 512

typedef __attribute__((ext_vector_type(8))) short bf16x8;
typedef __attribute__((ext_vector_type(4))) float f32x4;
typedef __attribute__((ext_vector_type(4))) short short4_t;
typedef __attribute__((ext_vector_type(4))) float float4_t;

__device__ __forceinline__ unsigned short f2bf(float f) {
  unsigned u = __float_as_uint(f);
  u += 0x7FFFu + ((u >> 16) & 1u);
  return (unsigned short)(u >> 16);
}

__device__ __forceinline__ float bf2f(unsigned short s) {
  return __uint_as_float(((unsigned)s) << 16);
}

__device__ __forceinline__ float tanh_fast(float x) {
  float e = __expf(2.0f * x);
  return 1.0f - 2.0f / (e + 1.0f);
}

#define GLOAD_LDS16(gsrc, ldst) \
  __builtin_amdgcn_global_load_lds((const __attribute__((address_space(1))) void*)(gsrc), \
                                   (__attribute__((address_space(3))) void*)(ldst), 16, 0, 0)

// ---------------- small utility kernels ----------------

__global__ void cvt_f32_bf16_k(const float* __restrict__ in, unsigned short* __restrict__ out, int n4) {
  int i = blockIdx.x * blockDim.x + threadIdx.x;
  if (i < n4) {
    float4_t v = ((const float4_t*)in)[i];
    short4_t s;
    s.x = (short)f2bf(v.x); s.y = (short)f2bf(v.y);
    s.z = (short)f2bf(v.z); s.w = (short)f2bf(v.w);
    ((short4_t*)out)[i] = s;
  }
}

// converts 3 equally-sized f32 buffers into one contiguous bf16 region
__global__ void cvt3_f32_bf16_k(const float* __restrict__ a, const float* __restrict__ b,
                                const float* __restrict__ c, unsigned short* __restrict__ out,
                                int n4each) {
  int i = blockIdx.x * blockDim.x + threadIdx.x;
  if (i >= 3 * n4each) return;
  int sel = i / n4each, j = i - sel * n4each;
  const float* src = (sel == 0) ? a : (sel == 1) ? b : c;
  float4_t v = ((const float4_t*)src)[j];
  short4_t s;
  s.x = (short)f2bf(v.x); s.y = (short)f2bf(v.y);
  s.z = (short)f2bf(v.z); s.w = (short)f2bf(v.w);
  ((short4_t*)out)[i] = s;
}

__global__ void prep_cluster_k(const int* __restrict__ vn, const int* __restrict__ nid,
                               int* __restrict__ cl, int* __restrict__ counts, int B) {
  int i = blockIdx.x * blockDim.x + threadIdx.x;
  if (i < B) {
    int c = vn[2 * nid[i] + 1];
    cl[i] = c;
    atomicAdd(&counts[c], 1);
  }
}

__global__ void prefix_k(const int* __restrict__ counts, int* __restrict__ starts,
                         int* __restrict__ cursor, int C) {
  __shared__ int sh[1024];
  int t = threadIdx.x;
  int v = (t < C) ? counts[t] : 0;
  sh[t] = v;
  __syncthreads();
  for (int off = 1; off < 1024; off <<= 1) {
    int x = (t >= off) ? sh[t - off] : 0;
    __syncthreads();
    sh[t] += x;
    __syncthreads();
  }
  if (t < C) { int st = sh[t] - v; starts[t] = st; cursor[t] = st; }
  if (t == 1023) starts[C] = sh[1023];
}

__global__ void scatter_k(const int* __restrict__ cl, int* __restrict__ cursor,
                          int* __restrict__ order, int B) {
  int i = blockIdx.x * blockDim.x + threadIdx.x;
  if (i < B) {
    int pos = atomicAdd(&cursor[cl[i]], 1);
    order[pos] = i;
  }
}

__device__ __forceinline__ unsigned enc_f(float f) {
  unsigned u = __float_as_uint(f);
  return (u & 0x80000000u) ? ~u : (u | 0x80000000u);
}
__device__ __forceinline__ float dec_f(unsigned u) {
  return __uint_as_float((u & 0x80000000u) ? (u & 0x7FFFFFFFu) : ~u);
}

__global__ void seg_max_k(const float* __restrict__ score, const int* __restrict__ cl,
                          unsigned* __restrict__ smax, int B) {
  int i = blockIdx.x * blockDim.x + threadIdx.x;
  if (i < B) atomicMax(&smax[cl[i]], enc_f(score[i]));
}

__global__ void seg_expsum_k(const float* __restrict__ score, const int* __restrict__ cl,
                             const unsigned* __restrict__ smax, float* __restrict__ ev,
                             float* __restrict__ denom, int B) {
  int i = blockIdx.x * blockDim.x + threadIdx.x;
  if (i < B) {
    int c = cl[i];
    float x = __expf(score[i] - dec_f(smax[c]));
    ev[i] = x;
    atomicAdd(&denom[c], x);
  }
}

// 256 threads; thread t owns d = 2t, 2t+1 (one uint = 2 bf16 per row); 4-row unroll
__global__ __launch_bounds__(256)
void ctx_k(const unsigned short* __restrict__ hbf, const float* __restrict__ ev,
           const int* __restrict__ order, const int* __restrict__ starts,
           const float* __restrict__ denom, float* __restrict__ ctx) {
  int c = blockIdx.x;
  int t = threadIdx.x;
  int s0 = starts[c], s1 = starts[c + 1];
  float a0 = 0.f, a1 = 0.f;
  int j = s0;
  for (; j + 3 < s1; j += 4) {
    int i0 = order[j], i1 = order[j + 1], i2 = order[j + 2], i3 = order[j + 3];
    float e0 = ev[i0], e1 = ev[i1], e2 = ev[i2], e3 = ev[i3];
    unsigned u0 = *(const unsigned*)(hbf + (size_t)i0 * D_DIM + t * 2);
    unsigned u1 = *(const unsigned*)(hbf + (size_t)i1 * D_DIM + t * 2);
    unsigned u2 = *(const unsigned*)(hbf + (size_t)i2 * D_DIM + t * 2);
    unsigned u3 = *(const unsigned*)(hbf + (size_t)i3 * D_DIM + t * 2);
    a0 += e0 * bf2f((unsigned short)u0) + e1 * bf2f((unsigned short)u1)
        + e2 * bf2f((unsigned short)u2) + e3 * bf2f((unsigned short)u3);
    a1 += e0 * bf2f((unsigned short)(u0 >> 16)) + e1 * bf2f((unsigned short)(u1 >> 16))
        + e2 * bf2f((unsigned short)(u2 >> 16)) + e3 * bf2f((unsigned short)(u3 >> 16));
  }
  for (; j < s1; ++j) {
    int i0 = order[j];
    float e0 = ev[i0];
    unsigned u0 = *(const unsigned*)(hbf + (size_t)i0 * D_DIM + t * 2);
    a0 += e0 * bf2f((unsigned short)u0);
    a1 += e0 * bf2f((unsigned short)(u0 >> 16));
  }
  float inv = 1.0f / denom[c];
  float2 r = make_float2(a0 * inv, a1 * inv);
  *(float2*)(&ctx[(size_t)c * D_DIM + t * 2]) = r;
}

// ------------- bf16 MFMA GEMM: 128x128 tile, BK=64, 2-phase dbuf -------------
// A: [M][512] bf16, Bw: [512][512] bf16 (row n = output col n)
// 1D grid = 4 * ceil(M/128), XCD-chunked swizzle; 256 threads (4 waves, 2x2 of 64x64)
// EPI 0: out[m][n] = acc + bias[n]
// EPI 1: atomicAdd(out[m], sum_n tanh(acc + qb[cl[m]][n]) * Ws[n])
// EPI 2: out[m][n] = tanh(acc + bias[n])
// LDS: 128 rows x 8 slots of 16B, swizzled slot' = slot ^ (row&7); global_load_lds
// writes linearly, the source address is pre-swizzled to match (rule #21).
template<int EPI>
__global__ __launch_bounds__(256)
void gemm128_k(const unsigned short* __restrict__ Abf,
               const unsigned short* __restrict__ Bw, int M,
               const float* __restrict__ qb, const int* __restrict__ cl,
               const float* __restrict__ Ws, const float* __restrict__ bias,
               float* __restrict__ out)
{
  __shared__ unsigned short As[2][128 * 64];
  __shared__ unsigned short Bs[2][128 * 64];
  __shared__ float red[128][2];
  __shared__ int clds[128];

  const int t = threadIdx.x;
  const int lane = t & 63;
  const int w = t >> 6;             // wave 0..3
  const int wr = w >> 1, wc = w & 1;
  const int l15 = lane & 15, l4 = lane >> 4;

  // XCD-chunked swizzle (bijective: gridDim.x % 8 == 0 for all our grids)
  const int nwg = gridDim.x;
  int id = blockIdx.x;
  if ((nwg & 7) == 0) id = (id & 7) * (nwg >> 3) + (id >> 3);
  const int n0 = (id & 3) * 128;    // n-block fastest -> siblings adjacent on one XCD
  const int m0 = (id >> 2) * 128;

  if (EPI == 1 && t < 128) {
    int gm = m0 + t;
    clds[t] = (gm < M) ? cl[gm] : 0;
  }

  // staging geometry: 16 chunks of 1KB per tile; wave w stages chunks w*4..w*4+3
  // lane covers row = chunk*8 + (lane>>3); lds slot = lane&7; source slot is
  // (lane&7) ^ (row&7) (inverse of read-side swizzle)
  const int rin = lane >> 3;
  const int sl = lane & 7;

  const unsigned short* srcA[4];
  const unsigned short* srcB[4];
  int dstOff[4];
  #pragma unroll
  for (int c = 0; c < 4; ++c) {
    int chunk = w * 4 + c;
    int row = chunk * 8 + rin;
    int slot = sl ^ (row & 7);
    int ga = m0 + row; if (ga > M - 1) ga = M - 1;
    srcA[c] = Abf + (size_t)ga * 512 + slot * 8;
    srcB[c] = Bw + (size_t)(n0 + row) * 512 + slot * 8;
    dstOff[c] = chunk * 1024;
  }

  // fragment LDS byte offsets (loop-invariant)
  int offA[4][2], offB[4][2];
  #pragma unroll
  for (int mi = 0; mi < 4; ++mi) {
    int row = wr * 64 + mi * 16 + l15;
    #pragma unroll
    for (int ks = 0; ks < 2; ++ks)
      offA[mi][ks] = row * 128 + (((ks * 4 + l4) ^ (row & 7)) * 16);
  }
  #pragma unroll
  for (int ni = 0; ni < 4; ++ni) {
    int row = wc * 64 + ni * 16 + l15;
    #pragma unroll
    for (int ks = 0; ks < 2; ++ks)
      offB[ni][ks] = row * 128 + (((ks * 4 + l4) ^ (row & 7)) * 16);
  }

  f32x4 acc[4][4];
  #pragma unroll
  for (int mi = 0; mi < 4; ++mi)
    #pragma unroll
    for (int ni = 0; ni < 4; ++ni)
      acc[mi][ni] = (f32x4){0.f, 0.f, 0.f, 0.f};

  // prologue: stage K-tile 0 into buffer 0, wait
  #pragma unroll
  for (int c = 0; c < 4; ++c) {
    GLOAD_LDS16(srcA[c], ((char*)As[0]) + dstOff[c]);
    GLOAD_LDS16(srcB[c], ((char*)Bs[0]) + dstOff[c]);
  }
  __syncthreads();

  // 2-phase main loop: prefetch tile it+1 into buf cur^1 while computing buf cur;
  // the single __syncthreads (compiler emits vmcnt(0) lgkmcnt(0) drain) per step
  // both publishes the prefetch and protects the buffer swap.
  #pragma unroll
  for (int it = 0; it < 8; ++it) {
    const int cur = it & 1;
    if (it < 7) {
      const int k1 = (it + 1) * 64;
      #pragma unroll
      for (int c = 0; c < 4; ++c) {
        GLOAD_LDS16(srcA[c] + k1, ((char*)As[cur ^ 1]) + dstOff[c]);
        GLOAD_LDS16(srcB[c] + k1, ((char*)Bs[cur ^ 1]) + dstOff[c]);
      }
    }
    #pragma unroll
    for (int ks = 0; ks < 2; ++ks) {
      bf16x8 af[4], bfv[4];
      #pragma unroll
      for (int mi = 0; mi < 4; ++mi)
        af[mi] = *(const bf16x8*)(((const char*)As[cur]) + offA[mi][ks]);
      #pragma unroll
      for (int ni = 0; ni < 4; ++ni)
        bfv[ni] = *(const bf16x8*)(((const char*)Bs[cur]) + offB[ni][ks]);
      #pragma unroll
      for (int mi = 0; mi < 4; ++mi)
        #pragma unroll
        for (int ni = 0; ni < 4; ++ni)
          acc[mi][ni] = __builtin_amdgcn_mfma_f32_16x16x32_bf16(af[mi], bfv[ni], acc[mi][ni], 0, 0, 0);
    }
    __syncthreads();
  }

  if (EPI == 0 || EPI == 2) {
    #pragma unroll
    for (int mi = 0; mi < 4; ++mi) {
      #pragma unroll
      for (int r = 0; r < 4; ++r) {
        int gm = m0 + wr * 64 + mi * 16 + l4 * 4 + r;
        if (gm < M) {
          #pragma unroll
          for (int ni = 0; ni < 4; ++ni) {
            int gcol = n0 + wc * 64 + ni * 16 + l15;
            float v = acc[mi][ni][r] + bias[gcol];
            if (EPI == 2) v = tanh_fast(v);
            out[(size_t)gm * 512 + gcol] = v;
          }
        }
      }
    }
  } else {
    // fused additive-attention partial score over this block's 128 cols
    #pragma unroll
    for (int mi = 0; mi < 4; ++mi) {
      #pragma unroll
      for (int r = 0; r < 4; ++r) {
        int rowt = wr * 64 + mi * 16 + l4 * 4 + r;
        int c = clds[rowt];
        const float* qrow = &qb[(size_t)c * 512 + n0 + wc * 64];
        float s = 0.f;
        #pragma unroll
        for (int ni = 0; ni < 4; ++ni) {
          int colw = ni * 16 + l15;
          float x = acc[mi][ni][r] + qrow[colw];
          s += tanh_fast(x) * Ws[n0 + wc * 64 + colw];
        }
        s += __shfl_xor(s, 1);
        s += __shfl_xor(s, 2);
        s += __shfl_xor(s, 4);
        s += __shfl_xor(s, 8);
        if (l15 == 0) red[rowt][wc] = s;
      }
    }
    __syncthreads();
    if (t < 128) {
      int gm = m0 + t;
      if (gm < M) atomicAdd(&out[gm], red[t][0] + red[t][1]);
    }
  }
}

// ---------------- host side ----------------

extern "C" void kernel_launch(void* const* d_in, const int* in_sizes, int n_in,
                              void* d_out, int out_size, void* d_ws, size_t ws_size,
                              hipStream_t stream) {
  const float* h  = (const float*)d_in[0];
  const float* g  = (const float*)d_in[1];
  const int*   vn = (const int*)d_in[2];
  const int*   nid= (const int*)d_in[3];
  const float* Wq = (const float*)d_in[4];
  const float* Wk = (const float*)d_in[5];
  const float* ab = (const float*)d_in[6];
  const float* Ws = (const float*)d_in[7];
  const float* W  = (const float*)d_in[9];
  const float* b  = (const float*)d_in[10];

  const int B = in_sizes[3];          // 100000
  const int C = in_sizes[1] / D_DIM;  // 1000

  char* wsb = (char*)d_ws;
  size_t off = 0;
  auto alloc = [&](size_t bytes) -> void* {
    void* p = wsb + off;
    off += (bytes + 255) & ~(size_t)255;
    return p;
  };

  unsigned short* hbf   = (unsigned short*)alloc((size_t)B * 512 * 2);
  unsigned short* gbf   = (unsigned short*)alloc((size_t)C * 512 * 2);
  unsigned short* ctxbf = (unsigned short*)alloc((size_t)C * 512 * 2);
  unsigned short* Wk_bf = (unsigned short*)alloc((size_t)512 * 512 * 2);  // contiguous
  unsigned short* Wq_bf = (unsigned short*)alloc((size_t)512 * 512 * 2);  // with Wk_bf
  unsigned short* W_bf  = (unsigned short*)alloc((size_t)512 * 512 * 2);  // and Wq_bf
  float* qb    = (float*)alloc((size_t)C * 512 * 4);
  float* ctx   = (float*)alloc((size_t)C * 512 * 4);
  float* score = (float*)alloc((size_t)B * 4);
  float* ev    = (float*)alloc((size_t)B * 4);
  int*   cl    = (int*)alloc((size_t)B * 4);
  int*   order = (int*)alloc((size_t)B * 4);
  int*      counts = (int*)alloc((size_t)C * 4);
  unsigned* smax   = (unsigned*)alloc((size_t)C * 4);
  float*    denom  = (float*)alloc((size_t)C * 4);
  int* starts = (int*)alloc((size_t)(C + 1) * 4);
  int* cursor = (int*)alloc((size_t)C * 4);
  (void)ws_size; (void)n_in; (void)out_size;

  // zero atomically-accumulated buffers each launch
  size_t zlen = (size_t)((char*)denom - (char*)counts) + (size_t)C * 4;
  hipMemsetAsync(counts, 0, zlen, stream);
  hipMemsetAsync(score, 0, (size_t)B * 4, stream);

  // conversions
  cvt_f32_bf16_k<<<(B * 512 / 4 + 255) / 256, 256, 0, stream>>>(h, hbf, B * 512 / 4);
  cvt_f32_bf16_k<<<(C * 512 / 4 + 255) / 256, 256, 0, stream>>>(g, gbf, C * 512 / 4);
  const int n4w = 512 * 512 / 4;
  cvt3_f32_bf16_k<<<(3 * n4w + 255) / 256, 256, 0, stream>>>(Wk, Wq, W, Wk_bf, n4w);

  prep_cluster_k<<<(B + 255) / 256, 256, 0, stream>>>(vn, nid, cl, counts, B);
  prefix_k<<<1, 1024, 0, stream>>>(counts, starts, cursor, C);
  scatter_k<<<(B + 255) / 256, 256, 0, stream>>>(cl, cursor, order, B);

  // qb = g @ Wq^T + attn_bias
  gemm128_k<0><<<4 * ((C + 127) / 128), 256, 0, stream>>>(
      gbf, Wq_bf, C, nullptr, nullptr, nullptr, ab, qb);

  // score[m] += sum over this N-block of tanh(h@Wk^T + qb[cl])·Ws  (bs dropped:
  // softmax is invariant to a constant shift)
  gemm128_k<1><<<4 * ((B + 127) / 128), 256, 0, stream>>>(
      hbf, Wk_bf, B, qb, cl, Ws, nullptr, score);

  seg_max_k<<<(B + 255) / 256, 256, 0, stream>>>(score, cl, smax, B);
  seg_expsum_k<<<(B + 255) / 256, 256, 0, stream>>>(score, cl, smax, ev, denom, B);
  ctx_k<<<C, 256, 0, stream>>>(hbf, ev, order, starts, denom, ctx);

  cvt_f32_bf16_k<<<(C * 512 / 4 + 255) / 256, 256, 0, stream>>>(ctx, ctxbf, C * 512 / 4);

  // out = tanh(ctx @ W^T + b)
  gemm128_k<2><<<4 * ((C + 127) / 128), 256, 0, stream>>>(
      ctxbf, W_bf, C, nullptr, nullptr, nullptr, b, (float*)d_out);
}

// Round 4
// 254.152 us; speedup vs baseline: 1.2469x; 1.0303x over previous
//
#include <hip/hip_runtime.h>
#include <stdint.h>

#define D_DIM 512

typedef __attribute__((ext_vector_type(8))) short bf16x8;
typedef __attribute__((ext_vector_type(4))) float f32x4;
typedef __attribute__((ext_vector_type(4))) short short4_t;
typedef __attribute__((ext_vector_type(4))) float float4_t;

__device__ __forceinline__ unsigned short f2bf(float f) {
  unsigned u = __float_as_uint(f);
  u += 0x7FFFu + ((u >> 16) & 1u);
  return (unsigned short)(u >> 16);
}

__device__ __forceinline__ float bf2f(unsigned short s) {
  return __uint_as_float(((unsigned)s) << 16);
}

__device__ __forceinline__ float tanh_fast(float x) {
  float e = __expf(2.0f * x);
  return 1.0f - 2.0f / (e + 1.0f);
}

#define GLOAD_LDS16(gsrc, ldst) \
  __builtin_amdgcn_global_load_lds((const __attribute__((address_space(1))) void*)(gsrc), \
                                   (__attribute__((address_space(3))) void*)(ldst), 16, 0, 0)

// ---------------- small utility kernels ----------------

__global__ void cvt_f32_bf16_k(const float* __restrict__ in, unsigned short* __restrict__ out, int n4) {
  int i = blockIdx.x * blockDim.x + threadIdx.x;
  if (i < n4) {
    float4_t v = ((const float4_t*)in)[i];
    short4_t s;
    s.x = (short)f2bf(v.x); s.y = (short)f2bf(v.y);
    s.z = (short)f2bf(v.z); s.w = (short)f2bf(v.w);
    ((short4_t*)out)[i] = s;
  }
}

// converts 3 equally-sized f32 buffers into one contiguous bf16 region
__global__ void cvt3_f32_bf16_k(const float* __restrict__ a, const float* __restrict__ b,
                                const float* __restrict__ c, unsigned short* __restrict__ out,
                                int n4each) {
  int i = blockIdx.x * blockDim.x + threadIdx.x;
  if (i >= 3 * n4each) return;
  int sel = i / n4each, j = i - sel * n4each;
  const float* src = (sel == 0) ? a : (sel == 1) ? b : c;
  float4_t v = ((const float4_t*)src)[j];
  short4_t s;
  s.x = (short)f2bf(v.x); s.y = (short)f2bf(v.y);
  s.z = (short)f2bf(v.z); s.w = (short)f2bf(v.w);
  ((short4_t*)out)[i] = s;
}

__global__ void prep_cluster_k(const int* __restrict__ vn, const int* __restrict__ nid,
                               int* __restrict__ cl, int* __restrict__ counts, int B) {
  int i = blockIdx.x * blockDim.x + threadIdx.x;
  if (i < B) {
    int c = vn[2 * nid[i] + 1];
    cl[i] = c;
    atomicAdd(&counts[c], 1);
  }
}

__global__ void prefix_k(const int* __restrict__ counts, int* __restrict__ starts,
                         int* __restrict__ cursor, int C) {
  __shared__ int sh[1024];
  int t = threadIdx.x;
  int v = (t < C) ? counts[t] : 0;
  sh[t] = v;
  __syncthreads();
  for (int off = 1; off < 1024; off <<= 1) {
    int x = (t >= off) ? sh[t - off] : 0;
    __syncthreads();
    sh[t] += x;
    __syncthreads();
  }
  if (t < C) { int st = sh[t] - v; starts[t] = st; cursor[t] = st; }
  if (t == 1023) starts[C] = sh[1023];
}

__global__ void scatter_k(const int* __restrict__ cl, int* __restrict__ cursor,
                          int* __restrict__ order, int B) {
  int i = blockIdx.x * blockDim.x + threadIdx.x;
  if (i < B) {
    int pos = atomicAdd(&cursor[cl[i]], 1);
    order[pos] = i;
  }
}

__device__ __forceinline__ unsigned enc_f(float f) {
  unsigned u = __float_as_uint(f);
  return (u & 0x80000000u) ? ~u : (u | 0x80000000u);
}
__device__ __forceinline__ float dec_f(unsigned u) {
  return __uint_as_float((u & 0x80000000u) ? (u & 0x7FFFFFFFu) : ~u);
}

__global__ void seg_max_k(const float* __restrict__ score, const int* __restrict__ cl,
                          unsigned* __restrict__ smax, int B) {
  int i = blockIdx.x * blockDim.x + threadIdx.x;
  if (i < B) atomicMax(&smax[cl[i]], enc_f(score[i]));
}

__global__ void seg_expsum_k(const float* __restrict__ score, const int* __restrict__ cl,
                             const unsigned* __restrict__ smax, float* __restrict__ ev,
                             float* __restrict__ denom, int B) {
  int i = blockIdx.x * blockDim.x + threadIdx.x;
  if (i < B) {
    int c = cl[i];
    float x = __expf(score[i] - dec_f(smax[c]));
    ev[i] = x;
    atomicAdd(&denom[c], x);
  }
}

// 256 threads; thread t owns d = 2t, 2t+1 (one uint = 2 bf16 per row); 4-row unroll
__global__ __launch_bounds__(256)
void ctx_k(const unsigned short* __restrict__ hbf, const float* __restrict__ ev,
           const int* __restrict__ order, const int* __restrict__ starts,
           const float* __restrict__ denom, float* __restrict__ ctx) {
  int c = blockIdx.x;
  int t = threadIdx.x;
  int s0 = starts[c], s1 = starts[c + 1];
  float a0 = 0.f, a1 = 0.f;
  int j = s0;
  for (; j + 3 < s1; j += 4) {
    int i0 = order[j], i1 = order[j + 1], i2 = order[j + 2], i3 = order[j + 3];
    float e0 = ev[i0], e1 = ev[i1], e2 = ev[i2], e3 = ev[i3];
    unsigned u0 = *(const unsigned*)(hbf + (size_t)i0 * D_DIM + t * 2);
    unsigned u1 = *(const unsigned*)(hbf + (size_t)i1 * D_DIM + t * 2);
    unsigned u2 = *(const unsigned*)(hbf + (size_t)i2 * D_DIM + t * 2);
    unsigned u3 = *(const unsigned*)(hbf + (size_t)i3 * D_DIM + t * 2);
    a0 += e0 * bf2f((unsigned short)u0) + e1 * bf2f((unsigned short)u1)
        + e2 * bf2f((unsigned short)u2) + e3 * bf2f((unsigned short)u3);
    a1 += e0 * bf2f((unsigned short)(u0 >> 16)) + e1 * bf2f((unsigned short)(u1 >> 16))
        + e2 * bf2f((unsigned short)(u2 >> 16)) + e3 * bf2f((unsigned short)(u3 >> 16));
  }
  for (; j < s1; ++j) {
    int i0 = order[j];
    float e0 = ev[i0];
    unsigned u0 = *(const unsigned*)(hbf + (size_t)i0 * D_DIM + t * 2);
    a0 += e0 * bf2f((unsigned short)u0);
    a1 += e0 * bf2f((unsigned short)(u0 >> 16));
  }
  float inv = 1.0f / denom[c];
  float2 r = make_float2(a0 * inv, a1 * inv);
  *(float2*)(&ctx[(size_t)c * D_DIM + t * 2]) = r;
}

// ------ bf16 MFMA GEMM: 128x128 tile, BK=64, counted-vmcnt dbuf pipeline ------
// A: [M][512] bf16, Bw: [512][512] bf16 (row n = output col n)
// 1D grid = 4 * ceil(M/128), XCD-chunked swizzle; 256 threads (4 waves, 2x2 of 64x64)
// EPI 0: out[m][n] = acc + bias[n]
// EPI 1: atomicAdd(out[m], sum_n tanh(acc + qb[cl[m]][n]) * Ws[n])
// EPI 2: out[m][n] = tanh(acc + bias[n])
// K-loop (T3/T4): per step, issue tile t+1's 8 global_load_lds into the buffer
// freed at the previous end-barrier, then s_waitcnt vmcnt(8) (drains tile t ONLY,
// keeps t+1 in flight), s_barrier, MFMA, s_barrier. Never vmcnt(0) mid-loop.
template<int EPI>
__global__ __launch_bounds__(256)
void gemm128_k(const unsigned short* __restrict__ Abf,
               const unsigned short* __restrict__ Bw, int M,
               const float* __restrict__ qb, const int* __restrict__ cl,
               const float* __restrict__ Ws, const float* __restrict__ bias,
               float* __restrict__ out)
{
  __shared__ unsigned short As[2][128 * 64];
  __shared__ unsigned short Bs[2][128 * 64];
  __shared__ float red[128][2];
  __shared__ int clds[128];

  const int t = threadIdx.x;
  const int lane = t & 63;
  const int w = t >> 6;             // wave 0..3
  const int wr = w >> 1, wc = w & 1;
  const int l15 = lane & 15, l4 = lane >> 4;

  // XCD-chunked swizzle (bijective: gridDim.x % 8 == 0 for all our grids)
  const int nwg = gridDim.x;
  int id = blockIdx.x;
  if ((nwg & 7) == 0) id = (id & 7) * (nwg >> 3) + (id >> 3);
  const int n0 = (id & 3) * 128;    // n-block fastest -> siblings adjacent on one XCD
  const int m0 = (id >> 2) * 128;

  // clds load BEFORE any staging issue so its vmcnt-wait (compiler-inserted)
  // doesn't perturb the counted pipeline below.
  if (EPI == 1 && t < 128) {
    int gm = m0 + t;
    clds[t] = (gm < M) ? cl[gm] : 0;
  }
  __builtin_amdgcn_sched_barrier(0);

  // staging geometry: 16 chunks of 1KB per tile; wave w stages chunks w*4..w*4+3
  // lane covers row = chunk*8 + (lane>>3); lds slot = lane&7; source slot is
  // (lane&7) ^ (row&7) (inverse of read-side swizzle)
  const int rin = lane >> 3;
  const int sl = lane & 7;

  const unsigned short* srcA[4];
  const unsigned short* srcB[4];
  int dstOff[4];
  #pragma unroll
  for (int c = 0; c < 4; ++c) {
    int chunk = w * 4 + c;
    int row = chunk * 8 + rin;
    int slot = sl ^ (row & 7);
    int ga = m0 + row; if (ga > M - 1) ga = M - 1;
    srcA[c] = Abf + (size_t)ga * 512 + slot * 8;
    srcB[c] = Bw + (size_t)(n0 + row) * 512 + slot * 8;
    dstOff[c] = chunk * 1024;
  }

  // fragment LDS byte offsets (loop-invariant)
  int offA[4][2], offB[4][2];
  #pragma unroll
  for (int mi = 0; mi < 4; ++mi) {
    int row = wr * 64 + mi * 16 + l15;
    #pragma unroll
    for (int ks = 0; ks < 2; ++ks)
      offA[mi][ks] = row * 128 + (((ks * 4 + l4) ^ (row & 7)) * 16);
  }
  #pragma unroll
  for (int ni = 0; ni < 4; ++ni) {
    int row = wc * 64 + ni * 16 + l15;
    #pragma unroll
    for (int ks = 0; ks < 2; ++ks)
      offB[ni][ks] = row * 128 + (((ks * 4 + l4) ^ (row & 7)) * 16);
  }

  f32x4 acc[4][4];
  #pragma unroll
  for (int mi = 0; mi < 4; ++mi)
    #pragma unroll
    for (int ni = 0; ni < 4; ++ni)
      acc[mi][ni] = (f32x4){0.f, 0.f, 0.f, 0.f};

  // prologue: issue tile 0 into buffer 0 (no barrier -- the loop's counted
  // wait + barrier at the top of step 0 publishes it)
  #pragma unroll
  for (int c = 0; c < 4; ++c) {
    GLOAD_LDS16(srcA[c], ((char*)As[0]) + dstOff[c]);
    GLOAD_LDS16(srcB[c], ((char*)Bs[0]) + dstOff[c]);
  }
  __builtin_amdgcn_sched_barrier(0);

  #pragma unroll
  for (int it = 0; it < 8; ++it) {
    const int cur = it & 1;
    if (it < 7) {
      // issue next tile into buf cur^1 (its readers finished at previous
      // end-barrier); these stay IN FLIGHT across the wait below
      const int k1 = (it + 1) * 64;
      #pragma unroll
      for (int c = 0; c < 4; ++c) {
        GLOAD_LDS16(srcA[c] + k1, ((char*)As[cur ^ 1]) + dstOff[c]);
        GLOAD_LDS16(srcB[c] + k1, ((char*)Bs[cur ^ 1]) + dstOff[c]);
      }
      __builtin_amdgcn_sched_barrier(0);
      asm volatile("s_waitcnt vmcnt(8)" ::: "memory");  // drain tile it only
    } else {
      asm volatile("s_waitcnt vmcnt(0)" ::: "memory");  // last tile: drain all
    }
    __builtin_amdgcn_sched_barrier(0);
    __builtin_amdgcn_s_barrier();     // all waves' tile-it loads have landed
    __builtin_amdgcn_sched_barrier(0);

    #pragma unroll
    for (int ks = 0; ks < 2; ++ks) {
      bf16x8 af[4], bfv[4];
      #pragma unroll
      for (int mi = 0; mi < 4; ++mi)
        af[mi] = *(const bf16x8*)(((const char*)As[cur]) + offA[mi][ks]);
      #pragma unroll
      for (int ni = 0; ni < 4; ++ni)
        bfv[ni] = *(const bf16x8*)(((const char*)Bs[cur]) + offB[ni][ks]);
      #pragma unroll
      for (int mi = 0; mi < 4; ++mi)
        #pragma unroll
        for (int ni = 0; ni < 4; ++ni)
          acc[mi][ni] = __builtin_amdgcn_mfma_f32_16x16x32_bf16(af[mi], bfv[ni], acc[mi][ni], 0, 0, 0);
    }
    __builtin_amdgcn_sched_barrier(0);
    __builtin_amdgcn_s_barrier();     // frees buf cur for tile it+2's loads
    __builtin_amdgcn_sched_barrier(0);
  }

  if (EPI == 0 || EPI == 2) {
    #pragma unroll
    for (int mi = 0; mi < 4; ++mi) {
      #pragma unroll
      for (int r = 0; r < 4; ++r) {
        int gm = m0 + wr * 64 + mi * 16 + l4 * 4 + r;
        if (gm < M) {
          #pragma unroll
          for (int ni = 0; ni < 4; ++ni) {
            int gcol = n0 + wc * 64 + ni * 16 + l15;
            float v = acc[mi][ni][r] + bias[gcol];
            if (EPI == 2) v = tanh_fast(v);
            out[(size_t)gm * 512 + gcol] = v;
          }
        }
      }
    }
  } else {
    // fused additive-attention partial score over this block's 128 cols
    #pragma unroll
    for (int mi = 0; mi < 4; ++mi) {
      #pragma unroll
      for (int r = 0; r < 4; ++r) {
        int rowt = wr * 64 + mi * 16 + l4 * 4 + r;
        int c = clds[rowt];
        const float* qrow = &qb[(size_t)c * 512 + n0 + wc * 64];
        float s = 0.f;
        #pragma unroll
        for (int ni = 0; ni < 4; ++ni) {
          int colw = ni * 16 + l15;
          float x = acc[mi][ni][r] + qrow[colw];
          s += tanh_fast(x) * Ws[n0 + wc * 64 + colw];
        }
        s += __shfl_xor(s, 1);
        s += __shfl_xor(s, 2);
        s += __shfl_xor(s, 4);
        s += __shfl_xor(s, 8);
        if (l15 == 0) red[rowt][wc] = s;
      }
    }
    __syncthreads();
    if (t < 128) {
      int gm = m0 + t;
      if (gm < M) atomicAdd(&out[gm], red[t][0] + red[t][1]);
    }
  }
}

// ---------------- host side ----------------

extern "C" void kernel_launch(void* const* d_in, const int* in_sizes, int n_in,
                              void* d_out, int out_size, void* d_ws, size_t ws_size,
                              hipStream_t stream) {
  const float* h  = (const float*)d_in[0];
  const float* g  = (const float*)d_in[1];
  const int*   vn = (const int*)d_in[2];
  const int*   nid= (const int*)d_in[3];
  const float* Wq = (const float*)d_in[4];
  const float* Wk = (const float*)d_in[5];
  const float* ab = (const float*)d_in[6];
  const float* Ws = (const float*)d_in[7];
  const float* W  = (const float*)d_in[9];
  const float* b  = (const float*)d_in[10];

  const int B = in_sizes[3];          // 100000
  const int C = in_sizes[1] / D_DIM;  // 1000

  char* wsb = (char*)d_ws;
  size_t off = 0;
  auto alloc = [&](size_t bytes) -> void* {
    void* p = wsb + off;
    off += (bytes + 255) & ~(size_t)255;
    return p;
  };

  unsigned short* hbf   = (unsigned short*)alloc((size_t)B * 512 * 2);
  unsigned short* gbf   = (unsigned short*)alloc((size_t)C * 512 * 2);
  unsigned short* ctxbf = (unsigned short*)alloc((size_t)C * 512 * 2);
  unsigned short* Wk_bf = (unsigned short*)alloc((size_t)512 * 512 * 2);  // contiguous
  unsigned short* Wq_bf = (unsigned short*)alloc((size_t)512 * 512 * 2);  // with Wk_bf
  unsigned short* W_bf  = (unsigned short*)alloc((size_t)512 * 512 * 2);  // and Wq_bf
  float* qb    = (float*)alloc((size_t)C * 512 * 4);
  float* ctx   = (float*)alloc((size_t)C * 512 * 4);
  float* score = (float*)alloc((size_t)B * 4);
  float* ev    = (float*)alloc((size_t)B * 4);
  int*   cl    = (int*)alloc((size_t)B * 4);
  int*   order = (int*)alloc((size_t)B * 4);
  int*      counts = (int*)alloc((size_t)C * 4);
  unsigned* smax   = (unsigned*)alloc((size_t)C * 4);
  float*    denom  = (float*)alloc((size_t)C * 4);
  int* starts = (int*)alloc((size_t)(C + 1) * 4);
  int* cursor = (int*)alloc((size_t)C * 4);
  (void)ws_size; (void)n_in; (void)out_size;

  // zero atomically-accumulated buffers each launch
  size_t zlen = (size_t)((char*)denom - (char*)counts) + (size_t)C * 4;
  hipMemsetAsync(counts, 0, zlen, stream);
  hipMemsetAsync(score, 0, (size_t)B * 4, stream);

  // conversions
  cvt_f32_bf16_k<<<(B * 512 / 4 + 255) / 256, 256, 0, stream>>>(h, hbf, B * 512 / 4);
  cvt_f32_bf16_k<<<(C * 512 / 4 + 255) / 256, 256, 0, stream>>>(g, gbf, C * 512 / 4);
  const int n4w = 512 * 512 / 4;
  cvt3_f32_bf16_k<<<(3 * n4w + 255) / 256, 256, 0, stream>>>(Wk, Wq, W, Wk_bf, n4w);

  prep_cluster_k<<<(B + 255) / 256, 256, 0, stream>>>(vn, nid, cl, counts, B);
  prefix_k<<<1, 1024, 0, stream>>>(counts, starts, cursor, C);
  scatter_k<<<(B + 255) / 256, 256, 0, stream>>>(cl, cursor, order, B);

  // qb = g @ Wq^T + attn_bias
  gemm128_k<0><<<4 * ((C + 127) / 128), 256, 0, stream>>>(
      gbf, Wq_bf, C, nullptr, nullptr, nullptr, ab, qb);

  // score[m] += sum over this N-block of tanh(h@Wk^T + qb[cl])·Ws  (bs dropped:
  // softmax is invariant to a constant shift)
  gemm128_k<1><<<4 * ((B + 127) / 128), 256, 0, stream>>>(
      hbf, Wk_bf, B, qb, cl, Ws, nullptr, score);

  seg_max_k<<<(B + 255) / 256, 256, 0, stream>>>(score, cl, smax, B);
  seg_expsum_k<<<(B + 255) / 256, 256, 0, stream>>>(score, cl, smax, ev, denom, B);
  ctx_k<<<C, 256, 0, stream>>>(hbf, ev, order, starts, denom, ctx);

  cvt_f32_bf16_k<<<(C * 512 / 4 + 255) / 256, 256, 0, stream>>>(ctx, ctxbf, C * 512 / 4);

  // out = tanh(ctx @ W^T + b)
  gemm128_k<2><<<4 * ((C + 127) / 128), 256, 0, stream>>>(
      ctxbf, W_bf, C, nullptr, nullptr, nullptr, b, (float*)d_out);
}

// Round 5
// 242.581 us; speedup vs baseline: 1.3064x; 1.0477x over previous
//
#include <hip/hip_runtime.h>
#include <stdint.h>

#define D_DIM 512

typedef __attribute__((ext_vector_type(8))) short bf16x8;
typedef __attribute__((ext_vector_type(4))) float f32x4;
typedef __attribute__((ext_vector_type(4))) short short4_t;
typedef __attribute__((ext_vector_type(4))) float float4_t;

__device__ __forceinline__ unsigned short f2bf(float f) {
  unsigned u = __float_as_uint(f);
  u += 0x7FFFu + ((u >> 16) & 1u);
  return (unsigned short)(u >> 16);
}

__device__ __forceinline__ float bf2f(unsigned short s) {
  return __uint_as_float(((unsigned)s) << 16);
}

__device__ __forceinline__ float tanh_fast(float x) {
  float e = __expf(2.0f * x);
  return 1.0f - 2.0f / (e + 1.0f);
}

#define GLOAD_LDS16(gsrc, ldst) \
  __builtin_amdgcn_global_load_lds((const __attribute__((address_space(1))) void*)(gsrc), \
                                   (__attribute__((address_space(3))) void*)(ldst), 16, 0, 0)

// ---------------- small utility kernels ----------------

__global__ void cvt_f32_bf16_k(const float* __restrict__ in, unsigned short* __restrict__ out, int n4) {
  int i = blockIdx.x * blockDim.x + threadIdx.x;
  if (i < n4) {
    float4_t v = ((const float4_t*)in)[i];
    short4_t s;
    s.x = (short)f2bf(v.x); s.y = (short)f2bf(v.y);
    s.z = (short)f2bf(v.z); s.w = (short)f2bf(v.w);
    ((short4_t*)out)[i] = s;
  }
}

// converts 3 equally-sized f32 buffers into one contiguous bf16 region
__global__ void cvt3_f32_bf16_k(const float* __restrict__ a, const float* __restrict__ b,
                                const float* __restrict__ c, unsigned short* __restrict__ out,
                                int n4each) {
  int i = blockIdx.x * blockDim.x + threadIdx.x;
  if (i >= 3 * n4each) return;
  int sel = i / n4each, j = i - sel * n4each;
  const float* src = (sel == 0) ? a : (sel == 1) ? b : c;
  float4_t v = ((const float4_t*)src)[j];
  short4_t s;
  s.x = (short)f2bf(v.x); s.y = (short)f2bf(v.y);
  s.z = (short)f2bf(v.z); s.w = (short)f2bf(v.w);
  ((short4_t*)out)[i] = s;
}

__global__ void prep_cluster_k(const int* __restrict__ vn, const int* __restrict__ nid,
                               int* __restrict__ cl, int* __restrict__ counts, int B) {
  int i = blockIdx.x * blockDim.x + threadIdx.x;
  if (i < B) {
    int c = vn[2 * nid[i] + 1];
    cl[i] = c;
    atomicAdd(&counts[c], 1);
  }
}

__global__ void prefix_k(const int* __restrict__ counts, int* __restrict__ starts,
                         int* __restrict__ cursor, int C) {
  __shared__ int sh[1024];
  int t = threadIdx.x;
  int v = (t < C) ? counts[t] : 0;
  sh[t] = v;
  __syncthreads();
  for (int off = 1; off < 1024; off <<= 1) {
    int x = (t >= off) ? sh[t - off] : 0;
    __syncthreads();
    sh[t] += x;
    __syncthreads();
  }
  if (t < C) { int st = sh[t] - v; starts[t] = st; cursor[t] = st; }
  if (t == 1023) starts[C] = sh[1023];
}

__global__ void scatter_k(const int* __restrict__ cl, int* __restrict__ cursor,
                          int* __restrict__ order, int B) {
  int i = blockIdx.x * blockDim.x + threadIdx.x;
  if (i < B) {
    int pos = atomicAdd(&cursor[cl[i]], 1);
    order[pos] = i;
  }
}

__device__ __forceinline__ unsigned enc_f(float f) {
  unsigned u = __float_as_uint(f);
  return (u & 0x80000000u) ? ~u : (u | 0x80000000u);
}
__device__ __forceinline__ float dec_f(unsigned u) {
  return __uint_as_float((u & 0x80000000u) ? (u & 0x7FFFFFFFu) : ~u);
}

__global__ void seg_max_k(const float* __restrict__ score, const int* __restrict__ cl,
                          unsigned* __restrict__ smax, int B) {
  int i = blockIdx.x * blockDim.x + threadIdx.x;
  if (i < B) atomicMax(&smax[cl[i]], enc_f(score[i]));
}

__global__ void seg_expsum_k(const float* __restrict__ score, const int* __restrict__ cl,
                             const unsigned* __restrict__ smax, float* __restrict__ ev,
                             float* __restrict__ denom, int B) {
  int i = blockIdx.x * blockDim.x + threadIdx.x;
  if (i < B) {
    int c = cl[i];
    float x = __expf(score[i] - dec_f(smax[c]));
    ev[i] = x;
    atomicAdd(&denom[c], x);
  }
}

// 256 threads; thread t owns d = 2t, 2t+1 (one uint = 2 bf16 per row); 4-row unroll
__global__ __launch_bounds__(256)
void ctx_k(const unsigned short* __restrict__ hbf, const float* __restrict__ ev,
           const int* __restrict__ order, const int* __restrict__ starts,
           const float* __restrict__ denom, float* __restrict__ ctx) {
  int c = blockIdx.x;
  int t = threadIdx.x;
  int s0 = starts[c], s1 = starts[c + 1];
  float a0 = 0.f, a1 = 0.f;
  int j = s0;
  for (; j + 3 < s1; j += 4) {
    int i0 = order[j], i1 = order[j + 1], i2 = order[j + 2], i3 = order[j + 3];
    float e0 = ev[i0], e1 = ev[i1], e2 = ev[i2], e3 = ev[i3];
    unsigned u0 = *(const unsigned*)(hbf + (size_t)i0 * D_DIM + t * 2);
    unsigned u1 = *(const unsigned*)(hbf + (size_t)i1 * D_DIM + t * 2);
    unsigned u2 = *(const unsigned*)(hbf + (size_t)i2 * D_DIM + t * 2);
    unsigned u3 = *(const unsigned*)(hbf + (size_t)i3 * D_DIM + t * 2);
    a0 += e0 * bf2f((unsigned short)u0) + e1 * bf2f((unsigned short)u1)
        + e2 * bf2f((unsigned short)u2) + e3 * bf2f((unsigned short)u3);
    a1 += e0 * bf2f((unsigned short)(u0 >> 16)) + e1 * bf2f((unsigned short)(u1 >> 16))
        + e2 * bf2f((unsigned short)(u2 >> 16)) + e3 * bf2f((unsigned short)(u3 >> 16));
  }
  for (; j < s1; ++j) {
    int i0 = order[j];
    float e0 = ev[i0];
    unsigned u0 = *(const unsigned*)(hbf + (size_t)i0 * D_DIM + t * 2);
    a0 += e0 * bf2f((unsigned short)u0);
    a1 += e0 * bf2f((unsigned short)(u0 >> 16));
  }
  float inv = 1.0f / denom[c];
  float2 r = make_float2(a0 * inv, a1 * inv);
  *(float2*)(&ctx[(size_t)c * D_DIM + t * 2]) = r;
}

// --- bf16 MFMA GEMM: 128x128 tile, BK=32, counted-vmcnt dbuf, 34KB LDS ---
// A: [M][512] bf16, Bw: [512][512] bf16 (row n = output col n)
// 1D grid = 4 * ceil(M/128), XCD-chunked swizzle; 256 threads (4 waves, 2x2 of 64x64)
// EPI 0: out[m][n] = acc + bias[n]
// EPI 1: atomicAdd(out[m], sum_n tanh(acc + qb[cl[m]][n]) * Ws[n])
// EPI 2: out[m][n] = tanh(acc + bias[n])
// LDS per tile: 128 rows x 4 slots of 16B (64B rows). Swizzle: phys_slot =
// slot ^ ((row ^ row>>2)&3) => ds_read_b128 is <=2-way (free). global_load_lds
// writes linearly; the SOURCE address carries the inverse swizzle (rule #21).
// Small LDS (2 tile-pairs = 32KB) -> 4 blocks/CU resident: TLP covers latency,
// counted vmcnt keeps one tile in flight per wave (never vmcnt(0) mid-loop).
template<int EPI>
__global__ __launch_bounds__(256)
void gemm128_k(const unsigned short* __restrict__ Abf,
               const unsigned short* __restrict__ Bw, int M,
               const float* __restrict__ qb, const int* __restrict__ cl,
               const float* __restrict__ Ws, const float* __restrict__ bias,
               float* __restrict__ out)
{
  __shared__ unsigned short As[2][128 * 32];
  __shared__ unsigned short Bs[2][128 * 32];
  __shared__ float red[128][2];
  __shared__ int clds[128];

  const int t = threadIdx.x;
  const int lane = t & 63;
  const int w = t >> 6;             // wave 0..3
  const int wr = w >> 1, wc = w & 1;
  const int l15 = lane & 15, l4 = lane >> 4;

  // XCD-chunked swizzle (bijective: gridDim.x % 8 == 0 for all our grids)
  const int nwg = gridDim.x;
  int id = blockIdx.x;
  if ((nwg & 7) == 0) id = (id & 7) * (nwg >> 3) + (id >> 3);
  const int n0 = (id & 3) * 128;    // n-block fastest -> siblings adjacent on one XCD
  const int m0 = (id >> 2) * 128;

  // clds load BEFORE any staging issue so its compiler-inserted vmcnt wait
  // doesn't perturb the counted pipeline below.
  if (EPI == 1 && t < 128) {
    int gm = m0 + t;
    clds[t] = (gm < M) ? cl[gm] : 0;
  }
  __builtin_amdgcn_sched_barrier(0);

  // staging: per operand tile (8KB) = 8 chunks of 1KB; wave w stages chunks
  // {2w, 2w+1}. Within a chunk: row = chunk*16 + (lane>>2), lds slot = lane&3,
  // source slot = (lane&3) ^ swz(row), swz(row) = (row ^ (row>>2)) & 3.
  const int rin = lane >> 2;
  const int sl = lane & 3;

  const unsigned short* srcA[2];
  const unsigned short* srcB[2];
  int dstOff[2];
  #pragma unroll
  for (int c = 0; c < 2; ++c) {
    int chunk = w * 2 + c;
    int row = chunk * 16 + rin;
    int slot = sl ^ ((row ^ (row >> 2)) & 3);
    int ga = m0 + row; if (ga > M - 1) ga = M - 1;
    srcA[c] = Abf + (size_t)ga * 512 + slot * 8;
    srcB[c] = Bw + (size_t)(n0 + row) * 512 + slot * 8;
    dstOff[c] = chunk * 1024;
  }

  // fragment LDS byte offsets (loop-invariant): lane reads row, 16B slot l4
  int offA[4], offB[4];
  #pragma unroll
  for (int mi = 0; mi < 4; ++mi) {
    int row = wr * 64 + mi * 16 + l15;
    offA[mi] = row * 64 + ((l4 ^ ((row ^ (row >> 2)) & 3)) * 16);
  }
  #pragma unroll
  for (int ni = 0; ni < 4; ++ni) {
    int row = wc * 64 + ni * 16 + l15;
    offB[ni] = row * 64 + ((l4 ^ ((row ^ (row >> 2)) & 3)) * 16);
  }

  f32x4 acc[4][4];
  #pragma unroll
  for (int mi = 0; mi < 4; ++mi)
    #pragma unroll
    for (int ni = 0; ni < 4; ++ni)
      acc[mi][ni] = (f32x4){0.f, 0.f, 0.f, 0.f};

  // prologue: issue tile 0 into buffer 0
  #pragma unroll
  for (int c = 0; c < 2; ++c) {
    GLOAD_LDS16(srcA[c], ((char*)As[0]) + dstOff[c]);
    GLOAD_LDS16(srcB[c], ((char*)Bs[0]) + dstOff[c]);
  }
  __builtin_amdgcn_sched_barrier(0);

  #pragma unroll
  for (int it = 0; it < 16; ++it) {
    const int cur = it & 1;
    if (it < 15) {
      // issue next tile into buf cur^1 (readers done at previous end-barrier);
      // stays IN FLIGHT across the counted wait below
      const int k1 = (it + 1) * 32;
      #pragma unroll
      for (int c = 0; c < 2; ++c) {
        GLOAD_LDS16(srcA[c] + k1, ((char*)As[cur ^ 1]) + dstOff[c]);
        GLOAD_LDS16(srcB[c] + k1, ((char*)Bs[cur ^ 1]) + dstOff[c]);
      }
      __builtin_amdgcn_sched_barrier(0);
      asm volatile("s_waitcnt vmcnt(4)" ::: "memory");  // drain tile it only
    } else {
      asm volatile("s_waitcnt vmcnt(0)" ::: "memory");  // last tile: drain all
    }
    __builtin_amdgcn_sched_barrier(0);
    __builtin_amdgcn_s_barrier();     // all waves' tile-it loads have landed
    __builtin_amdgcn_sched_barrier(0);

    {
      bf16x8 af[4], bfv[4];
      #pragma unroll
      for (int mi = 0; mi < 4; ++mi)
        af[mi] = *(const bf16x8*)(((const char*)As[cur]) + offA[mi]);
      #pragma unroll
      for (int ni = 0; ni < 4; ++ni)
        bfv[ni] = *(const bf16x8*)(((const char*)Bs[cur]) + offB[ni]);
      #pragma unroll
      for (int mi = 0; mi < 4; ++mi)
        #pragma unroll
        for (int ni = 0; ni < 4; ++ni)
          acc[mi][ni] = __builtin_amdgcn_mfma_f32_16x16x32_bf16(af[mi], bfv[ni], acc[mi][ni], 0, 0, 0);
    }
    __builtin_amdgcn_sched_barrier(0);
    __builtin_amdgcn_s_barrier();     // frees buf cur for tile it+2's loads
    __builtin_amdgcn_sched_barrier(0);
  }

  if (EPI == 0 || EPI == 2) {
    #pragma unroll
    for (int mi = 0; mi < 4; ++mi) {
      #pragma unroll
      for (int r = 0; r < 4; ++r) {
        int gm = m0 + wr * 64 + mi * 16 + l4 * 4 + r;
        if (gm < M) {
          #pragma unroll
          for (int ni = 0; ni < 4; ++ni) {
            int gcol = n0 + wc * 64 + ni * 16 + l15;
            float v = acc[mi][ni][r] + bias[gcol];
            if (EPI == 2) v = tanh_fast(v);
            out[(size_t)gm * 512 + gcol] = v;
          }
        }
      }
    }
  } else {
    // fused additive-attention partial score over this block's 128 cols
    #pragma unroll
    for (int mi = 0; mi < 4; ++mi) {
      #pragma unroll
      for (int r = 0; r < 4; ++r) {
        int rowt = wr * 64 + mi * 16 + l4 * 4 + r;
        int c = clds[rowt];
        const float* qrow = &qb[(size_t)c * 512 + n0 + wc * 64];
        float s = 0.f;
        #pragma unroll
        for (int ni = 0; ni < 4; ++ni) {
          int colw = ni * 16 + l15;
          float x = acc[mi][ni][r] + qrow[colw];
          s += tanh_fast(x) * Ws[n0 + wc * 64 + colw];
        }
        s += __shfl_xor(s, 1);
        s += __shfl_xor(s, 2);
        s += __shfl_xor(s, 4);
        s += __shfl_xor(s, 8);
        if (l15 == 0) red[rowt][wc] = s;
      }
    }
    __syncthreads();
    if (t < 128) {
      int gm = m0 + t;
      if (gm < M) atomicAdd(&out[gm], red[t][0] + red[t][1]);
    }
  }
}

// ---------------- host side ----------------

extern "C" void kernel_launch(void* const* d_in, const int* in_sizes, int n_in,
                              void* d_out, int out_size, void* d_ws, size_t ws_size,
                              hipStream_t stream) {
  const float* h  = (const float*)d_in[0];
  const float* g  = (const float*)d_in[1];
  const int*   vn = (const int*)d_in[2];
  const int*   nid= (const int*)d_in[3];
  const float* Wq = (const float*)d_in[4];
  const float* Wk = (const float*)d_in[5];
  const float* ab = (const float*)d_in[6];
  const float* Ws = (const float*)d_in[7];
  const float* W  = (const float*)d_in[9];
  const float* b  = (const float*)d_in[10];

  const int B = in_sizes[3];          // 100000
  const int C = in_sizes[1] / D_DIM;  // 1000

  char* wsb = (char*)d_ws;
  size_t off = 0;
  auto alloc = [&](size_t bytes) -> void* {
    void* p = wsb + off;
    off += (bytes + 255) & ~(size_t)255;
    return p;
  };

  unsigned short* hbf   = (unsigned short*)alloc((size_t)B * 512 * 2);
  unsigned short* gbf   = (unsigned short*)alloc((size_t)C * 512 * 2);
  unsigned short* ctxbf = (unsigned short*)alloc((size_t)C * 512 * 2);
  unsigned short* Wk_bf = (unsigned short*)alloc((size_t)512 * 512 * 2);  // contiguous
  unsigned short* Wq_bf = (unsigned short*)alloc((size_t)512 * 512 * 2);  // with Wk_bf
  unsigned short* W_bf  = (unsigned short*)alloc((size_t)512 * 512 * 2);  // and Wq_bf
  float* qb    = (float*)alloc((size_t)C * 512 * 4);
  float* ctx   = (float*)alloc((size_t)C * 512 * 4);
  float* score = (float*)alloc((size_t)B * 4);
  float* ev    = (float*)alloc((size_t)B * 4);
  int*   cl    = (int*)alloc((size_t)B * 4);
  int*   order = (int*)alloc((size_t)B * 4);
  int*      counts = (int*)alloc((size_t)C * 4);
  unsigned* smax   = (unsigned*)alloc((size_t)C * 4);
  float*    denom  = (float*)alloc((size_t)C * 4);
  int* starts = (int*)alloc((size_t)(C + 1) * 4);
  int* cursor = (int*)alloc((size_t)C * 4);
  (void)ws_size; (void)n_in; (void)out_size;

  // zero atomically-accumulated buffers each launch
  size_t zlen = (size_t)((char*)denom - (char*)counts) + (size_t)C * 4;
  hipMemsetAsync(counts, 0, zlen, stream);
  hipMemsetAsync(score, 0, (size_t)B * 4, stream);

  // conversions
  cvt_f32_bf16_k<<<(B * 512 / 4 + 255) / 256, 256, 0, stream>>>(h, hbf, B * 512 / 4);
  cvt_f32_bf16_k<<<(C * 512 / 4 + 255) / 256, 256, 0, stream>>>(g, gbf, C * 512 / 4);
  const int n4w = 512 * 512 / 4;
  cvt3_f32_bf16_k<<<(3 * n4w + 255) / 256, 256, 0, stream>>>(Wk, Wq, W, Wk_bf, n4w);

  prep_cluster_k<<<(B + 255) / 256, 256, 0, stream>>>(vn, nid, cl, counts, B);
  prefix_k<<<1, 1024, 0, stream>>>(counts, starts, cursor, C);
  scatter_k<<<(B + 255) / 256, 256, 0, stream>>>(cl, cursor, order, B);

  // qb = g @ Wq^T + attn_bias
  gemm128_k<0><<<4 * ((C + 127) / 128), 256, 0, stream>>>(
      gbf, Wq_bf, C, nullptr, nullptr, nullptr, ab, qb);

  // score[m] += sum over this N-block of tanh(h@Wk^T + qb[cl])·Ws  (bs dropped:
  // softmax is invariant to a constant shift)
  gemm128_k<1><<<4 * ((B + 127) / 128), 256, 0, stream>>>(
      hbf, Wk_bf, B, qb, cl, Ws, nullptr, score);

  seg_max_k<<<(B + 255) / 256, 256, 0, stream>>>(score, cl, smax, B);
  seg_expsum_k<<<(B + 255) / 256, 256, 0, stream>>>(score, cl, smax, ev, denom, B);
  ctx_k<<<C, 256, 0, stream>>>(hbf, ev, order, starts, denom, ctx);

  cvt_f32_bf16_k<<<(C * 512 / 4 + 255) / 256, 256, 0, stream>>>(ctx, ctxbf, C * 512 / 4);

  // out = tanh(ctx @ W^T + b)
  gemm128_k<2><<<4 * ((C + 127) / 128), 256, 0, stream>>>(
      ctxbf, W_bf, C, nullptr, nullptr, nullptr, b, (float*)d_out);
}